// Round 1
// baseline (738.866 us; speedup 1.0000x reference)
//
#include <hip/hip_runtime.h>

// Causal linear attention (ELU+1 feature map), chunked 3-pass formulation.
// B=4, T=8192, H=16, D=64, fp32.
// ws layout: 4096 records (bh*NCH + c) of REC=4160 floats: M[64][64] then z[64].
// ws requirement: 4096*4160*4 = 68.2 MB.

#define EPS_ 1e-6f

constexpr int Bc  = 4;
constexpr int Tc  = 8192;
constexpr int Hc  = 16;
constexpr int Dc  = 64;
constexpr int CH  = 128;          // chunk length for records
constexpr int NCH = Tc / CH;      // 64 chunks per (b,h)
constexpr int BHc = Bc * Hc;      // 64
constexpr int REC = Dc * Dc + Dc; // 4160 floats per record

__device__ __forceinline__ float phi_f(float x) {
    // elu(x)+1 : x>0 ? x+1 : exp(x)
    return x > 0.f ? x + 1.f : __expf(x);
}

// ---------------- pass 1: per-chunk sums M_c = sum phi(k) v^T, z_c = sum phi(k) ----
__global__ __launch_bounds__(256) void k_chunksum(const float* __restrict__ kin,
                                                  const float* __restrict__ vin,
                                                  float* __restrict__ ws) {
    const int chunk = blockIdx.x;            // bh*NCH + c
    const int bh = chunk / NCH, c = chunk % NCH;
    const int b  = bh / Hc,    h = bh % Hc;
    const int t0 = c * CH;
    const int tid = threadIdx.x;

    __shared__ float ktl[64][Dc];
    __shared__ float vtl[64][Dc];

    const int dg = tid >> 4;   // 0..15  (d rows dg*4..+3)
    const int eg = tid & 15;   // 0..15  (e cols eg*4..+3)

    float acc[4][4];
    #pragma unroll
    for (int i = 0; i < 4; i++)
        #pragma unroll
        for (int j = 0; j < 4; j++) acc[i][j] = 0.f;
    float zac[4] = {0.f, 0.f, 0.f, 0.f};

    const int lrow = tid >> 2;           // 0..63
    const int lcb  = (tid & 3) << 4;     // 0,16,32,48

    for (int tt = 0; tt < CH; tt += 64) {
        __syncthreads();
        const size_t gofs = ((((size_t)b * Tc) + (t0 + tt + lrow)) * Hc + h) * Dc + lcb;
        const float4* kp = (const float4*)(kin + gofs);
        const float4* vp = (const float4*)(vin + gofs);
        #pragma unroll
        for (int i = 0; i < 4; i++) {
            float4 kk = kp[i];
            kk.x = phi_f(kk.x); kk.y = phi_f(kk.y); kk.z = phi_f(kk.z); kk.w = phi_f(kk.w);
            *(float4*)&ktl[lrow][lcb + i * 4] = kk;
            *(float4*)&vtl[lrow][lcb + i * 4] = vp[i];
        }
        __syncthreads();
        #pragma unroll 4
        for (int t = 0; t < 64; ++t) {
            float4 ka = *(const float4*)&ktl[t][dg << 2];
            float4 va = *(const float4*)&vtl[t][eg << 2];
            float kaa[4] = {ka.x, ka.y, ka.z, ka.w};
            float vaa[4] = {va.x, va.y, va.z, va.w};
            #pragma unroll
            for (int i = 0; i < 4; i++)
                #pragma unroll
                for (int j = 0; j < 4; j++)
                    acc[i][j] += kaa[i] * vaa[j];
            if (eg == 0) {
                #pragma unroll
                for (int i = 0; i < 4; i++) zac[i] += kaa[i];
            }
        }
    }
    float* rec = ws + (size_t)chunk * REC;
    #pragma unroll
    for (int i = 0; i < 4; i++) {
        *(float4*)&rec[(dg * 4 + i) * Dc + eg * 4] =
            make_float4(acc[i][0], acc[i][1], acc[i][2], acc[i][3]);
    }
    if (eg == 0) {
        *(float4*)&rec[Dc * Dc + dg * 4] = make_float4(zac[0], zac[1], zac[2], zac[3]);
    }
}

// ---------------- pass 2: exclusive prefix over chunks, in place ----------------
__global__ __launch_bounds__(256) void k_prefix(float* __restrict__ ws) {
    const int bh = blockIdx.x;
    const int e  = blockIdx.y * 256 + threadIdx.x;
    if (e >= REC) return;
    float* p = ws + (size_t)bh * NCH * REC + e;
    float run = 0.f;
    for (int c = 0; c < NCH; ++c) {
        float x = p[(size_t)c * REC];
        p[(size_t)c * REC] = run;
        run += x;
    }
}

// ---------------- pass 3: outputs. one block per 64-row half-chunk --------------
__global__ __launch_bounds__(256) void k_output(const float* __restrict__ qin,
                                                const float* __restrict__ kin,
                                                const float* __restrict__ vin,
                                                const float* __restrict__ ws,
                                                float* __restrict__ outp) {
    const int unit = blockIdx.x;                 // bh*(NCH*2) + c*2 + half
    const int bh   = unit / (NCH * 2);
    const int rem  = unit % (NCH * 2);
    const int c    = rem >> 1;
    const int half = rem & 1;
    const int b = bh / Hc, h = bh % Hc;
    const int t0 = c * CH + half * 64;           // first output row (global t)
    const int tid = threadIdx.x;
    const int rg = tid >> 4;                     // 0..15 row group (rows rg*4..+3)
    const int cg = tid & 15;                     // 0..15 col group (cols cg*4..+3)

    __shared__ float qT[Dc][64];    // phi(q) transposed: [d][t_local]
    __shared__ float bkw[64 * 68];  // union: S(4096)+z(64) | kT[d][s] 64x(68) | W[t][s] 64x(68)
    __shared__ float vt[64 * Dc];   // [s][e]
    __shared__ float den[64];

    // load phi(q) transposed
    {
        const int row = tid >> 2;                // 0..63 local t
        const int cb  = (tid & 3) << 4;          // 0,16,32,48
        const size_t gofs = ((((size_t)b * Tc) + (t0 + row)) * Hc + h) * Dc + cb;
        const float4* qp = (const float4*)(qin + gofs);
        #pragma unroll
        for (int i = 0; i < 4; i++) {
            float4 qq = qp[i];
            qT[cb + i * 4 + 0][row] = phi_f(qq.x);
            qT[cb + i * 4 + 1][row] = phi_f(qq.y);
            qT[cb + i * 4 + 2][row] = phi_f(qq.z);
            qT[cb + i * 4 + 3][row] = phi_f(qq.w);
        }
    }
    // load S (+z) record into bkw (flat: S[d*64+e], z at 4096+d)
    {
        const float* rec = ws + (size_t)(bh * NCH + c) * REC;
        for (int i = tid; i < REC / 4; i += 256) {
            *(float4*)&bkw[i * 4] = ((const float4*)rec)[i];
        }
    }
    __syncthreads();

    // den0 = eps + phi(q_t) . z_start
    if (tid < 64) {
        float s = 0.f;
        #pragma unroll 8
        for (int d = 0; d < Dc; ++d) s += qT[d][tid] * bkw[Dc * Dc + d];
        den[tid] = s + EPS_;
    }

    // GEMM1: acc = PhiQ(64x64) * S(64x64)
    float acc[4][4];
    #pragma unroll
    for (int i = 0; i < 4; i++)
        #pragma unroll
        for (int j = 0; j < 4; j++) acc[i][j] = 0.f;
    #pragma unroll 4
    for (int d = 0; d < Dc; ++d) {
        float4 a4 = *(const float4*)&qT[d][rg * 4];
        float4 b4 = *(const float4*)&bkw[d * Dc + cg * 4];
        float aa[4] = {a4.x, a4.y, a4.z, a4.w};
        float bb[4] = {b4.x, b4.y, b4.z, b4.w};
        #pragma unroll
        for (int i = 0; i < 4; i++)
            #pragma unroll
            for (int j = 0; j < 4; j++)
                acc[i][j] += aa[i] * bb[j];
    }

    // intra-chunk s-tiles: lower half (half=0) needs tile 0; upper half needs 0 and 1
    for (int st = 0; st <= half; ++st) {
        __syncthreads();   // previous users of bkw/vt done
        {
            const int row = tid >> 2;            // s-local 0..63
            const int cb  = (tid & 3) << 4;
            const int sg  = c * CH + st * 64 + row;  // global s row
            const size_t gofs = ((((size_t)b * Tc) + sg) * Hc + h) * Dc + cb;
            const float4* kp = (const float4*)(kin + gofs);
            const float4* vp = (const float4*)(vin + gofs);
            #pragma unroll
            for (int i = 0; i < 4; i++) {
                float4 kk = kp[i];
                bkw[(cb + i * 4 + 0) * 68 + row] = phi_f(kk.x);
                bkw[(cb + i * 4 + 1) * 68 + row] = phi_f(kk.y);
                bkw[(cb + i * 4 + 2) * 68 + row] = phi_f(kk.z);
                bkw[(cb + i * 4 + 3) * 68 + row] = phi_f(kk.w);
                *(float4*)&vt[row * Dc + cb + i * 4] = vp[i];
            }
        }
        __syncthreads();
        // W-GEMM: w[t][s] = phi(q_t) . phi(k_s)
        float w[4][4];
        #pragma unroll
        for (int i = 0; i < 4; i++)
            #pragma unroll
            for (int j = 0; j < 4; j++) w[i][j] = 0.f;
        #pragma unroll 4
        for (int d = 0; d < Dc; ++d) {
            float4 a4 = *(const float4*)&qT[d][rg * 4];
            float4 k4 = *(const float4*)&bkw[d * 68 + cg * 4];
            float aa[4] = {a4.x, a4.y, a4.z, a4.w};
            float kk[4] = {k4.x, k4.y, k4.z, k4.w};
            #pragma unroll
            for (int i = 0; i < 4; i++)
                #pragma unroll
                for (int j = 0; j < 4; j++)
                    w[i][j] += aa[i] * kk[j];
        }
        // causal mask within chunk
        #pragma unroll
        for (int i = 0; i < 4; i++) {
            const int tch = half * 64 + rg * 4 + i;
            #pragma unroll
            for (int j = 0; j < 4; j++) {
                const int sch = st * 64 + cg * 4 + j;
                if (sch > tch) w[i][j] = 0.f;
            }
        }
        // den += rowsum(w), reduced across the 16 col-groups (16 consecutive lanes)
        #pragma unroll
        for (int i = 0; i < 4; i++) {
            float rs = w[i][0] + w[i][1] + w[i][2] + w[i][3];
            rs += __shfl_xor(rs, 8, 16);
            rs += __shfl_xor(rs, 4, 16);
            rs += __shfl_xor(rs, 2, 16);
            rs += __shfl_xor(rs, 1, 16);
            if (cg == 0) den[rg * 4 + i] += rs;
        }
        __syncthreads();   // all kT reads done before overwriting bkw with W
        #pragma unroll
        for (int i = 0; i < 4; i++) {
            *(float4*)&bkw[(rg * 4 + i) * 68 + cg * 4] =
                make_float4(w[i][0], w[i][1], w[i][2], w[i][3]);
        }
        __syncthreads();   // W visible to all
        // GEMM2: acc += W(64x64) * V(64x64)
        #pragma unroll 2
        for (int s0 = 0; s0 < 64; s0 += 4) {
            float wv[4][4];
            #pragma unroll
            for (int i = 0; i < 4; i++) {
                float4 wr = *(const float4*)&bkw[(rg * 4 + i) * 68 + s0];
                wv[i][0] = wr.x; wv[i][1] = wr.y; wv[i][2] = wr.z; wv[i][3] = wr.w;
            }
            #pragma unroll
            for (int ss = 0; ss < 4; ++ss) {
                float4 vv = *(const float4*)&vt[(s0 + ss) * Dc + cg * 4];
                float vb[4] = {vv.x, vv.y, vv.z, vv.w};
                #pragma unroll
                for (int i = 0; i < 4; i++)
                    #pragma unroll
                    for (int j = 0; j < 4; j++)
                        acc[i][j] += wv[i][ss] * vb[j];
            }
        }
    }

    // epilogue: divide by den, store
    #pragma unroll
    for (int i = 0; i < 4; i++) {
        const float inv = 1.0f / den[rg * 4 + i];
        const size_t gofs = ((((size_t)b * Tc) + (t0 + rg * 4 + i)) * Hc + h) * Dc + cg * 4;
        *(float4*)(outp + gofs) =
            make_float4(acc[i][0] * inv, acc[i][1] * inv, acc[i][2] * inv, acc[i][3] * inv);
    }
}

extern "C" void kernel_launch(void* const* d_in, const int* in_sizes, int n_in,
                              void* d_out, int out_size, void* d_ws, size_t ws_size,
                              hipStream_t stream) {
    const float* q = (const float*)d_in[0];
    const float* k = (const float*)d_in[1];
    const float* v = (const float*)d_in[2];
    float* out = (float*)d_out;
    float* ws  = (float*)d_ws;   // needs 4096*4160*4 = 68.2 MB

    k_chunksum<<<BHc * NCH, 256, 0, stream>>>(k, v, ws);
    dim3 g2(BHc, (REC + 255) / 256);
    k_prefix<<<g2, 256, 0, stream>>>(ws);
    k_output<<<BHc * NCH * 2, 256, 0, stream>>>(q, k, v, ws, out);
}

// Round 2
// 567.079 us; speedup vs baseline: 1.3029x; 1.3029x over previous
//
#include <hip/hip_runtime.h>
#include <hip/hip_bf16.h>

// Causal linear attention (ELU+1), chunked 3-pass, bf16 MFMA formulation.
// B=4, T=8192, H=16, D=64, fp32 in/out.
// ws: 4096 records (bh*NCH+c) of REC=4160 fp32: S^T[e][d] (4096) then z[d] (64).
// ws requirement: 68.2 MB.

#define EPS_ 1e-6f

constexpr int Bc  = 4;
constexpr int Tc  = 8192;
constexpr int Hc  = 16;
constexpr int Dc  = 64;
constexpr int CH  = 128;          // chunk length
constexpr int NCH = Tc / CH;      // 64
constexpr int BHc = Bc * Hc;      // 64
constexpr int REC = Dc * Dc + Dc; // 4160

typedef short  bf16x8 __attribute__((ext_vector_type(8)));  // 8 bf16 (4 VGPRs)
typedef float  f32x4  __attribute__((ext_vector_type(4)));

__device__ __forceinline__ float phi_f(float x) {
    return x > 0.f ? x + 1.f : __expf(x);   // elu(x)+1
}
__device__ __forceinline__ unsigned short f2b(float x) {
    __hip_bfloat16 b = __float2bfloat16(x);          // round-to-nearest-even
    return __builtin_bit_cast(unsigned short, b);
}
__device__ __forceinline__ float b2f(unsigned short u) {
    return __uint_as_float(((unsigned)u) << 16);     // exact
}

// ---------------- pass 1: rec = [ S^T[e][d] = sum_s v[s][e] phi(k)[s][d] ; z[d] ] ----
__global__ __launch_bounds__(256) void k_chunksum(const float* __restrict__ kin,
                                                  const float* __restrict__ vin,
                                                  float* __restrict__ ws) {
    const int chunk = blockIdx.x;            // bh*NCH + c
    const int bh = chunk >> 6, c = chunk & (NCH - 1);
    const int b  = bh >> 4,    h = bh & 15;
    const int t0 = c * CH;
    const int tid = threadIdx.x;

    __shared__ unsigned short ktr[64][136];  // phiK^T [d][s], s=0..127
    __shared__ unsigned short vtr[64][136];  // V^T    [e][s]
    __shared__ float zred[4][64];

    // stage + transpose 128 rows of k,v
    {
        const int srow = tid >> 2;           // 0..63
        const int cb   = (tid & 3) << 4;     // 0,16,32,48
        #pragma unroll
        for (int sh = 0; sh < 2; ++sh) {
            const int s = srow + sh * 64;
            const size_t g = ((((size_t)b * Tc) + (t0 + s)) * Hc + h) * Dc + cb;
            const float4* kp = (const float4*)(kin + g);
            const float4* vp = (const float4*)(vin + g);
            #pragma unroll
            for (int i = 0; i < 4; i++) {
                float4 kk = kp[i];
                float4 vv = vp[i];
                ktr[cb + i*4 + 0][s] = f2b(phi_f(kk.x));
                ktr[cb + i*4 + 1][s] = f2b(phi_f(kk.y));
                ktr[cb + i*4 + 2][s] = f2b(phi_f(kk.z));
                ktr[cb + i*4 + 3][s] = f2b(phi_f(kk.w));
                vtr[cb + i*4 + 0][s] = f2b(vv.x);
                vtr[cb + i*4 + 1][s] = f2b(vv.y);
                vtr[cb + i*4 + 2][s] = f2b(vv.z);
                vtr[cb + i*4 + 3][s] = f2b(vv.w);
            }
        }
    }
    __syncthreads();

    // z[d] = sum_s phiK[s][d]  (sum the bf16-rounded values, fp32 accumulate)
    {
        const int d = tid & 63, part = tid >> 6;
        float zs = 0.f;
        #pragma unroll
        for (int j = 0; j < 4; j++) {
            bf16x8 kv = *(const bf16x8*)&ktr[d][part * 32 + j * 8];
            #pragma unroll
            for (int u = 0; u < 8; u++) zs += b2f((unsigned short)kv[u]);
        }
        zred[part][d] = zs;
    }

    // MFMA: C[e][d] += V^T[e][s] * phiK[s][d]
    const int w = tid >> 6, lane = tid & 63;
    const int l15 = lane & 15, quad = lane >> 4;
    f32x4 acc[4];
    #pragma unroll
    for (int nt = 0; nt < 4; nt++) acc[nt] = (f32x4){0.f, 0.f, 0.f, 0.f};
    #pragma unroll
    for (int ks = 0; ks < 4; ks++) {
        bf16x8 a = *(const bf16x8*)&vtr[16 * w + l15][quad * 8 + ks * 32];
        #pragma unroll
        for (int nt = 0; nt < 4; nt++) {
            bf16x8 bb = *(const bf16x8*)&ktr[16 * nt + l15][quad * 8 + ks * 32];
            acc[nt] = __builtin_amdgcn_mfma_f32_16x16x32_bf16(a, bb, acc[nt], 0, 0, 0);
        }
    }
    __syncthreads();   // zred complete

    float* rec = ws + (size_t)chunk * REC;
    #pragma unroll
    for (int nt = 0; nt < 4; nt++)
        #pragma unroll
        for (int r = 0; r < 4; r++) {
            const int e = 16 * w + quad * 4 + r;
            const int d = 16 * nt + l15;
            rec[e * 64 + d] = acc[nt][r];
        }
    if (tid < 64)
        rec[4096 + tid] = zred[0][tid] + zred[1][tid] + zred[2][tid] + zred[3][tid];
}

// ---------------- pass 2: exclusive prefix over chunks (fp32, elementwise) --------
__global__ __launch_bounds__(256) void k_prefix(float* __restrict__ ws) {
    const int bh = blockIdx.x;
    const int e  = blockIdx.y * 256 + threadIdx.x;
    if (e >= REC) return;
    float* p = ws + (size_t)bh * NCH * REC + e;
    float run = 0.f;
    for (int c = 0; c < NCH; ++c) {
        float x = p[(size_t)c * REC];
        p[(size_t)c * REC] = run;
        run += x;
    }
}

// ---------------- pass 3: outputs, one block per 64-row half-chunk ----------------
__global__ __launch_bounds__(256) void k_output(const float* __restrict__ qin,
                                                const float* __restrict__ kin,
                                                const float* __restrict__ vin,
                                                const float* __restrict__ ws,
                                                float* __restrict__ outp) {
    const int unit = blockIdx.x;                 // bh*(NCH*2) + c*2 + half
    const int bh   = unit >> 7;                  // / (NCH*2)
    const int rem  = unit & (NCH * 2 - 1);
    const int c    = rem >> 1;
    const int half = rem & 1;
    const int b = bh >> 4, h = bh & 15;
    const int t0 = c * CH + half * 64;           // first output row (global t)
    const int tid = threadIdx.x;
    const int w = tid >> 6, lane = tid & 63;
    const int l15 = lane & 15, quad = lane >> 4;

    __shared__ unsigned short qb[64][72];   // phiQ [t][d]
    __shared__ unsigned short swb[64][72];  // S^T[e][d], later W[t][s]
    __shared__ unsigned short kb[64][72];   // phiK [s][d]
    __shared__ unsigned short vb[64][72];   // V^T  [e][s]
    __shared__ float zsh[64];
    __shared__ float den[64];

    // stage phi(q) -> qb (row-major, bf16)
    {
        const int row = tid >> 2, cb = (tid & 3) << 4;
        const float4* qp = (const float4*)(qin + ((((size_t)b * Tc) + (t0 + row)) * Hc + h) * Dc + cb);
        #pragma unroll
        for (int i = 0; i < 4; i++) {
            float4 qq = qp[i];
            unsigned short* dst = &qb[row][cb + i * 4];
            dst[0] = f2b(phi_f(qq.x)); dst[1] = f2b(phi_f(qq.y));
            dst[2] = f2b(phi_f(qq.z)); dst[3] = f2b(phi_f(qq.w));
        }
    }
    // stage S^T -> swb (bf16), z -> zsh (fp32)
    {
        const float* rec = ws + (size_t)(bh * NCH + c) * REC;
        #pragma unroll
        for (int i = 0; i < 4; i++) {
            const int idx = tid + i * 256;       // float4 index, 0..1023
            float4 sv = ((const float4*)rec)[idx];
            const int flat = idx * 4, e = flat >> 6, d = flat & 63;
            unsigned short* dst = &swb[e][d];
            dst[0] = f2b(sv.x); dst[1] = f2b(sv.y); dst[2] = f2b(sv.z); dst[3] = f2b(sv.w);
        }
        if (tid < 16) {
            float4 zv = ((const float4*)(rec + 4096))[tid];
            zsh[tid * 4 + 0] = zv.x; zsh[tid * 4 + 1] = zv.y;
            zsh[tid * 4 + 2] = zv.z; zsh[tid * 4 + 3] = zv.w;
        }
    }
    __syncthreads();

    // den0 = eps + phiQ[t] . z
    if (tid < 64) {
        float s = 0.f;
        #pragma unroll
        for (int j = 0; j < 8; j++) {
            bf16x8 qv = *(const bf16x8*)&qb[tid][j * 8];
            #pragma unroll
            for (int u = 0; u < 8; u++) s += b2f((unsigned short)qv[u]) * zsh[j * 8 + u];
        }
        den[tid] = s + EPS_;
    }

    // GEMM1: acc[t][e] = phiQ[t][d] * S[d][e]   (B from S^T rows)
    f32x4 acc[4];
    #pragma unroll
    for (int nt = 0; nt < 4; nt++) acc[nt] = (f32x4){0.f, 0.f, 0.f, 0.f};
    #pragma unroll
    for (int ks = 0; ks < 2; ks++) {
        bf16x8 a = *(const bf16x8*)&qb[16 * w + l15][quad * 8 + ks * 32];
        #pragma unroll
        for (int nt = 0; nt < 4; nt++) {
            bf16x8 bb = *(const bf16x8*)&swb[16 * nt + l15][quad * 8 + ks * 32];
            acc[nt] = __builtin_amdgcn_mfma_f32_16x16x32_bf16(a, bb, acc[nt], 0, 0, 0);
        }
    }

    for (int st = 0; st <= half; ++st) {
        __syncthreads();   // GEMM1 reads of swb / previous tile users done
        // stage phiK -> kb (natural), V^T -> vb (transposed)
        {
            const int row = tid >> 2, cb = (tid & 3) << 4;
            const int sg = c * CH + st * 64 + row;
            const size_t g = ((((size_t)b * Tc) + sg) * Hc + h) * Dc + cb;
            const float4* kp = (const float4*)(kin + g);
            const float4* vp = (const float4*)(vin + g);
            #pragma unroll
            for (int i = 0; i < 4; i++) {
                float4 kk = kp[i];
                float4 vv = vp[i];
                unsigned short* kd = &kb[row][cb + i * 4];
                kd[0] = f2b(phi_f(kk.x)); kd[1] = f2b(phi_f(kk.y));
                kd[2] = f2b(phi_f(kk.z)); kd[3] = f2b(phi_f(kk.w));
                vb[cb + i * 4 + 0][row] = f2b(vv.x);
                vb[cb + i * 4 + 1][row] = f2b(vv.y);
                vb[cb + i * 4 + 2][row] = f2b(vv.z);
                vb[cb + i * 4 + 3][row] = f2b(vv.w);
            }
        }
        __syncthreads();

        // GEMM2: W[t][s] = phiQ[t][d] * phiK[s][d]
        f32x4 wt[4];
        #pragma unroll
        for (int nt = 0; nt < 4; nt++) wt[nt] = (f32x4){0.f, 0.f, 0.f, 0.f};
        #pragma unroll
        for (int ks = 0; ks < 2; ks++) {
            bf16x8 a = *(const bf16x8*)&qb[16 * w + l15][quad * 8 + ks * 32];
            #pragma unroll
            for (int nt = 0; nt < 4; nt++) {
                bf16x8 bb = *(const bf16x8*)&kb[16 * nt + l15][quad * 8 + ks * 32];
                wt[nt] = __builtin_amdgcn_mfma_f32_16x16x32_bf16(a, bb, wt[nt], 0, 0, 0);
            }
        }

        // mask, round to bf16, rowsum (of rounded values!), write W -> swb
        const int tbase = half * 64 + 16 * w + quad * 4;   // chunk-local t of reg r=0
        float rsum[4] = {0.f, 0.f, 0.f, 0.f};
        #pragma unroll
        for (int nt = 0; nt < 4; nt++) {
            const int sch = st * 64 + 16 * nt + l15;
            #pragma unroll
            for (int r = 0; r < 4; r++) {
                float val = (sch > tbase + r) ? 0.f : wt[nt][r];
                unsigned short wb16 = f2b(val);
                swb[16 * w + quad * 4 + r][16 * nt + l15] = wb16;
                rsum[r] += b2f(wb16);
            }
        }
        #pragma unroll
        for (int r = 0; r < 4; r++) {
            float rs = rsum[r];
            rs += __shfl_xor(rs, 8, 16);
            rs += __shfl_xor(rs, 4, 16);
            rs += __shfl_xor(rs, 2, 16);
            rs += __shfl_xor(rs, 1, 16);
            if (l15 == 0) den[16 * w + quad * 4 + r] += rs;
        }
        __syncthreads();   // W visible

        // GEMM3: acc[t][e] += W[t][s] * V[s][e]   (B from V^T rows)
        #pragma unroll
        for (int ks = 0; ks < 2; ks++) {
            bf16x8 a = *(const bf16x8*)&swb[16 * w + l15][quad * 8 + ks * 32];
            #pragma unroll
            for (int nt = 0; nt < 4; nt++) {
                bf16x8 bb = *(const bf16x8*)&vb[16 * nt + l15][quad * 8 + ks * 32];
                acc[nt] = __builtin_amdgcn_mfma_f32_16x16x32_bf16(a, bb, acc[nt], 0, 0, 0);
            }
        }
    }
    __syncthreads();   // den final

    // epilogue: out[t][e] = acc / den[t]
    #pragma unroll
    for (int r = 0; r < 4; r++) {
        const int t = 16 * w + quad * 4 + r;
        const float inv = 1.0f / den[t];
        const size_t gbase = ((((size_t)b * Tc) + (t0 + t)) * Hc + h) * Dc;
        #pragma unroll
        for (int nt = 0; nt < 4; nt++) {
            outp[gbase + 16 * nt + l15] = acc[nt][r] * inv;
        }
    }
}

extern "C" void kernel_launch(void* const* d_in, const int* in_sizes, int n_in,
                              void* d_out, int out_size, void* d_ws, size_t ws_size,
                              hipStream_t stream) {
    const float* q = (const float*)d_in[0];
    const float* k = (const float*)d_in[1];
    const float* v = (const float*)d_in[2];
    float* out = (float*)d_out;
    float* ws  = (float*)d_ws;   // 4096*4160*4 = 68.2 MB

    k_chunksum<<<BHc * NCH, 256, 0, stream>>>(k, v, ws);
    dim3 g2(BHc, (REC + 255) / 256);
    k_prefix<<<g2, 256, 0, stream>>>(ws);
    k_output<<<BHc * NCH * 2, 256, 0, stream>>>(q, k, v, ws, out);
}